// Round 3
// baseline (15.614 us; speedup 1.0000x reference)
//
#include <hip/hip_runtime.h>
#include <hip/hip_bf16.h>
#include <math.h>

#define A_ATOMS 64
#define AEVDIM  384   // 4*16 radial + 10*32 angular
#define PMAX    256   // pair chunk size

__global__ __launch_bounds__(256) void aev_kernel(
    const int*   __restrict__ species,   // (N, 64)
    const float* __restrict__ coords,    // (N, 64, 3)
    float*       __restrict__ out)       // (N, 64, 384)
{
    constexpr float PI  = 3.14159265358979323846f;
    constexpr float RCR = 5.2f;
    constexpr float RCA = 3.5f;

    const int bid  = blockIdx.x;     // n*64 + i
    const int n    = bid >> 6;
    const int i    = bid & 63;
    const int t    = threadIdx.x;    // 0..255
    const int lane = t & 63;
    const int wid  = t >> 6;         // wave id 0..3

    __shared__ float sh_aev[AEVDIM];
    __shared__ float s_cx[64], s_cy[64], s_cz[64];
    __shared__ int   s_spec[64];
    // compacted angular neighbor list (written by wave 0)
    __shared__ float s_ux[64], s_uy[64], s_uz[64], s_d[64], s_fc[64];
    __shared__ int   s_nspec[64];
    // per-pair precomputed data (chunked)
    __shared__ float p_ca[PMAX], p_sa[PMAX], p_davg[PMAX], p_fp2[PMAX];
    __shared__ int   p_dst[PMAX];

    // zero accumulator + stage coords/species in LDS
    for (int f = t; f < AEVDIM; f += 256) sh_aev[f] = 0.0f;
    if (t < 64) {
        const float* cb = coords + (size_t)n * (A_ATOMS * 3) + t * 3;
        s_cx[t] = cb[0]; s_cy[t] = cb[1]; s_cz[t] = cb[2];
        s_spec[t] = species[n * A_ATOMS + t];
    }
    __syncthreads();

    // every wave recomputes all 64 distances (lane = atom j)
    const float xi = s_cx[i], yi = s_cy[i], zi = s_cz[i];
    const float dx = s_cx[lane] - xi, dy = s_cy[lane] - yi, dz = s_cz[lane] - zi;
    const float d  = sqrtf(dx * dx + dy * dy + dz * dz);
    const bool  notself = (lane != i);
    const int   sj = s_spec[lane];

    // ---------------- radial: wave w handles shifts [4w, 4w+4)
    if (notself && d <= RCR) {
        const float fc = 0.5f * __cosf(PI * (d * (1.0f / RCR))) + 0.5f;
        const float q  = 0.25f * fc;
        float* dst = &sh_aev[sj * 16];
        #pragma unroll
        for (int rr = 0; rr < 4; ++rr) {
            const int   r   = wid * 4 + rr;
            const float shf = 0.9f + 0.26875f * (float)r;   // 0.9 + (5.2-0.9)/16 * r
            const float tt  = d - shf;
            atomicAdd(&dst[r], q * __expf(-16.0f * tt * tt));
        }
    }

    // ---------------- angular neighbor compaction (ballot identical across waves)
    const bool act = notself && (d <= RCA);
    const unsigned long long bm = __ballot(act);
    const int M = __popcll(bm);
    if (wid == 0 && act) {
        const int pos = __popcll(bm & ((1ull << lane) - 1ull));
        const float inv = 1.0f / d;
        s_ux[pos] = dx * inv; s_uy[pos] = dy * inv; s_uz[pos] = dz * inv;
        s_d[pos]  = d;
        s_fc[pos] = 0.5f * __cosf(PI * (d * (1.0f / RCA))) + 0.5f;
        s_nspec[pos] = sj;
    }
    __syncthreads();

    // cos/sin of SHF_Z[z] = pi/16*(2z+1)
    const float CZ[8] = { 0.980785280f,  0.831469612f,  0.555570233f,  0.195090322f,
                         -0.195090322f, -0.555570233f, -0.831469612f, -0.980785280f };
    const float SZ[8] = { 0.195090322f,  0.555570233f,  0.831469612f,  0.980785280f,
                          0.980785280f,  0.831469612f,  0.555570233f,  0.195090322f };

    const int nP = (M * (M - 1)) >> 1;   // unordered pairs (term symmetric in j,k)

    for (int pbase = 0; pbase < nP; pbase += PMAX) {
        const int chunkN = min(nP - pbase, PMAX);

        // ---- stage A: precompute per-pair data (decode + gathers done ONCE per pair)
        for (int idx = t; idx < chunkN; idx += 256) {
            int a = 0, rem = pbase + idx;
            while (rem >= (M - 1 - a)) { rem -= (M - 1 - a); ++a; }
            const int b = a + 1 + rem;

            const float dot = s_ux[a] * s_ux[b] + s_uy[a] * s_uy[b] + s_uz[a] * s_uz[b];
            const float ca  = 0.95f * dot;
            p_ca[idx]   = ca;
            p_sa[idx]   = sqrtf(fmaxf(0.0f, 1.0f - ca * ca));
            p_davg[idx] = 0.5f * (s_d[a] + s_d[b]);
            p_fp2[idx]  = 2.0f * s_fc[a] * s_fc[b];

            const int s1 = s_nspec[a], s2 = s_nspec[b];
            const int lo = (s1 < s2) ? s1 : s2;
            const int hi = (s1 < s2) ? s2 : s1;
            p_dst[idx]  = 64 + (((lo * (9 - lo)) >> 1) + (hi - lo)) * 32;
        }
        __syncthreads();

        // ---- stage B: task = (pair, aa); 1 expf + 8 fused z-terms + 8 atomics
        const int nTask = chunkN << 2;
        for (int task = t; task < nTask; task += 256) {
            const int idx = task >> 2;
            const int aa  = task & 3;
            const float ca   = p_ca[idx];
            const float sa   = p_sa[idx];
            const float shfa = 0.9f + 0.65f * (float)aa;    // 0.9 + (3.5-0.9)/4 * aa
            const float tt   = p_davg[idx] - shfa;
            const float base = p_fp2[idx] * __expf(-8.0f * tt * tt);
            float* dst = &sh_aev[p_dst[idx] + aa * 8];
            #pragma unroll
            for (int z = 0; z < 8; ++z) {
                const float c  = ca * CZ[z] + sa * SZ[z];
                float f1 = 0.5f * (1.0f + c);
                f1 = f1 * f1; f1 = f1 * f1; f1 = f1 * f1; f1 = f1 * f1; f1 = f1 * f1;
                atomicAdd(&dst[z], base * f1);
            }
        }
        __syncthreads();
    }

    // nP could be 0: the second sync above never ran, but all threads agree on nP,
    // so control flow is uniform — safe. Final sync before readout only needed if
    // the loop body executed; atomics from radial still need draining:
    __syncthreads();

    // ---------------- write out (n,i) row: 384 floats, coalesced
    float* o = out + (size_t)bid * AEVDIM;
    for (int f = t; f < AEVDIM; f += 256) o[f] = sh_aev[f];
}

extern "C" void kernel_launch(void* const* d_in, const int* in_sizes, int n_in,
                              void* d_out, int out_size, void* d_ws, size_t ws_size,
                              hipStream_t stream) {
    const int*   species = (const int*)d_in[0];
    const float* coords  = (const float*)d_in[1];
    float*       out     = (float*)d_out;
    const int N = in_sizes[0] / A_ATOMS;   // species is (N, 64)
    aev_kernel<<<N * A_ATOMS, 256, 0, stream>>>(species, coords, out);
}